// Round 13
// baseline (237.960 us; speedup 1.0000x reference)
//
#include <hip/hip_runtime.h>
#include <hip/hip_bf16.h>

#define N_ROWS 32768
#define NPAD   32832             // 171 blocks x 192 rows (pad rows zeroed)
#define M_ROWS 8192
#define D_DIM  384
#define K_NB   9
#define BN     64
#define RW     48                // rows per wave
#define RB     192               // rows per block (4 waves)
#define NMQ    8
#define MQ     (M_ROWS / NMQ)    // 1024 cols per block
#define TILES  (MQ / BN)         // 16
#define KS     3                 // K steps of 128

// key = y^2 - 2xy quantized: key' = (key + 256) / 2048 in [0,1]
#define QSCALE (1.0f / 2048.0f)
#define YOFF   0.125f
#define QSTEPF (2048.0f / 65535.0f)
#define QOFFB  256.0f
#define M2S    (-2.0f / 2048.0f)
#define BIGF   3.0e38f

#define BUFSZ  24576             // one B buffer = 64 rows x 384 fp8 (also B8 tile stride)
#define YS_OFF 49152             // LDS offset of Ys (2 KB);  total LDS 51200

typedef __attribute__((ext_vector_type(4))) int      i32x4;
typedef __attribute__((ext_vector_type(8))) int      i32x8;
typedef __attribute__((ext_vector_type(4))) float    f32x4;
typedef __attribute__((ext_vector_type(2))) unsigned u32x2;

#define GLDS(SRC, DST)                                                       \
  __builtin_amdgcn_global_load_lds(                                          \
      (const __attribute__((address_space(1))) void*)(SRC),                  \
      (__attribute__((address_space(3))) void*)(DST), 16, 0, 0)

#define MF(AF, B, C)                                                         \
  __builtin_amdgcn_mfma_scale_f32_16x16x128_f8f6f4(                          \
      (AF), (B), (C), 0, 0, 0, 0x7F7F7F7F, 0, 0x7F7F7F7F)

// ---- prep: f32 -> fp8(e4m3) rows (k-linear) + exact f32 norms; zero pad ----
__global__ __launch_bounds__(256) void FAPM_prep8(
    const float* __restrict__ emb, const float* __restrict__ mem,
    unsigned* __restrict__ A8, unsigned* __restrict__ B8,
    float* __restrict__ xn, float* __restrict__ yn) {
  const int lane = threadIdx.x & 63;
  const int row  = blockIdx.x * 4 + (threadIdx.x >> 6);
  const float* src;
  unsigned* dst;
  float* nptr;
  if (row >= N_ROWS && row < NPAD) {  // wave-uniform pad branch: zero the row
    unsigned* d = A8 + (size_t)row * 96;
    d[lane] = 0u;
    if (lane < 32) d[lane + 64] = 0u;
    if (lane == 0) xn[row] = 0.f;
    return;
  }
  if (row < N_ROWS) {
    src = emb + (size_t)row * D_DIM; dst = A8 + (size_t)row * 96; nptr = xn + row;
  } else {
    int r = row - NPAD;
    src = mem + (size_t)r * D_DIM; dst = B8 + (size_t)r * 96; nptr = yn + r;
  }
  float s = 0.f;
  {
    int dw = lane;
    f32x4 v = *(const f32x4*)(src + dw * 4);
    s += v.x * v.x + v.y * v.y + v.z * v.z + v.w * v.w;
    int pk = __builtin_amdgcn_cvt_pk_fp8_f32(v.x, v.y, 0, false);
    pk = __builtin_amdgcn_cvt_pk_fp8_f32(v.z, v.w, pk, true);
    dst[dw] = (unsigned)pk;
  }
  if (lane < 32) {
    int dw = lane + 64;
    f32x4 v = *(const f32x4*)(src + dw * 4);
    s += v.x * v.x + v.y * v.y + v.z * v.z + v.w * v.w;
    int pk = __builtin_amdgcn_cvt_pk_fp8_f32(v.x, v.y, 0, false);
    pk = __builtin_amdgcn_cvt_pk_fp8_f32(v.z, v.w, pk, true);
    dst[dw] = (unsigned)pk;
  }
#pragma unroll
  for (int dd = 1; dd < 64; dd <<= 1) s += __shfl_xor(s, dd);
  if (lane == 0) *nptr = s;
}

// packed u16 min/max
__device__ __forceinline__ unsigned pkmin(unsigned a, unsigned b) {
  unsigned d;
  asm("v_pk_min_u16 %0, %1, %2" : "=v"(d) : "v"(a), "v"(b));
  return d;
}
__device__ __forceinline__ unsigned pkmax(unsigned a, unsigned b) {
  unsigned d;
  asm("v_pk_max_u16 %0, %1, %2" : "=v"(d) : "v"(a), "v"(b));
  return d;
}

// insert packed candidate dp into packed sorted top-9 list
__device__ __forceinline__ void ins9(unsigned t[9], unsigned dp) {
#pragma unroll
  for (int j = 8; j >= 1; --j) t[j] = pkmin(t[j], pkmax(dp, t[j - 1]));
  t[0] = pkmin(t[0], dp);
}

// ---- 16-lane merge of per-lane sorted u16 lists; writes f32 key ascending ----
__device__ __forceinline__ void merge16i(unsigned t[9], float* dst, int sub) {
  for (int s = 0; s < K_NB; ++s) {
    unsigned m  = t[0];
    int      ml = sub;
#pragma unroll
    for (int dd = 1; dd < 16; dd <<= 1) {
      unsigned ov = (unsigned)__shfl_xor((int)m, dd);
      int      ol = __shfl_xor(ml, dd);
      bool take = (ov < m) || (ov == m && ol < ml);
      m  = take ? ov : m;
      ml = take ? ol : ml;
    }
    if (sub == ml) {
#pragma unroll
      for (int j = 0; j < 8; ++j) t[j] = t[j + 1];
      t[8] = 0xFFFFu;
    }
    if (sub == 0) dst[s] = (float)m * QSTEPF - QOFFB;  // key = y^2 - 2xy
  }
}

// ------- fused: MX-fp8 K=128, 48 rows/wave (3 waves/SIMD), key top-9 -------
__global__ __launch_bounds__(256, 3) void FAPM_fused(
    const unsigned char* __restrict__ A8, const unsigned char* __restrict__ B8,
    const float* __restrict__ yn, float* __restrict__ part) {
  // [0,48K): A stage (prologue, 2 rounds of 96 rows = 36KB), then
  //          B buf0 [0,24K) / buf1 [24K,48K). Subtile unit 1KB = 16 rows x
  //          one (ks,h) 16B-chunk column; lane l's 16B at subtile + l*16.
  // [48K,50K): Ys as unorm16 of (y^2/2048 + 0.125), 1024 entries.
  __shared__ __attribute__((aligned(128))) unsigned char LDS[51200];
  const int tid  = threadIdx.x;
  const int lane = tid & 63;
  const int w    = tid >> 6;          // wave 0..3
  const int sub  = lane & 15;
  const int grp  = lane >> 4;
  const int bx   = blockIdx.x;
  const int mq   = bx & (NMQ - 1);
  const int row0 = (bx >> 3) * RB;    // wave owns rows row0 + w*48 .. +47
  const int colbase = mq * MQ;

  // ---- Ys: each thread quantizes 4 y-norms ----
  {
    const float* yp = yn + colbase + tid * 4;
    f32x4 v = *(const f32x4*)yp;
    float a0 = fmaf(v.x, QSCALE, YOFF), a1 = fmaf(v.y, QSCALE, YOFF);
    float a2 = fmaf(v.z, QSCALE, YOFF), a3 = fmaf(v.w, QSCALE, YOFF);
    unsigned q0, q1;
    asm("v_cvt_pknorm_u16_f32 %0, %1, %2" : "=v"(q0) : "v"(a0), "v"(a1));
    asm("v_cvt_pknorm_u16_f32 %0, %1, %2" : "=v"(q1) : "v"(a2), "v"(a3));
    *(u32x2*)(&LDS[YS_OFF + tid * 8]) = (u32x2){q0, q1};
  }

  i32x8 af[3][KS];  // 72 regs: 3 row-blocks of 16, 3 K-steps of 128

  // ---- stage + read A: 2 rounds of 96 rows (36 subtiles) ----
#pragma unroll
  for (int h = 0; h < 2; ++h) {
    const int rowbase = row0 + h * 96;
#pragma unroll
    for (int j = 0; j < 9; ++j) {
      int u  = w * 9 + j;        // subtile 0..35
      int g  = u / 6;            // 16-row group 0..5
      int km = u - g * 6;
      int ks = km >> 1, h2 = km & 1;
      GLDS(A8 + (size_t)(rowbase + g * 16 + sub) * D_DIM + ks * 128 + grp * 32 + h2 * 16,
           LDS + u * 1024);
    }
    asm volatile("s_waitcnt vmcnt(0)" ::: "memory");
    __syncthreads();
    if ((w >> 1) == h) {
      const int q = w & 1;       // which 48-row half of this 96-row round
#pragma unroll
      for (int r = 0; r < 3; ++r)
#pragma unroll
        for (int ks = 0; ks < KS; ++ks) {
          const unsigned char* p =
              LDS + ((q * 3 + r) * 6 + ks * 2) * 1024 + lane * 16;
          *(i32x4*)&af[r][ks] = *(const i32x4*)p;
          *((i32x4*)&af[r][ks] + 1) = *(const i32x4*)(p + 1024);
        }
    }
    __syncthreads();  // reads drained before next overwrite
  }

  // ---- prime 2-deep B pipeline: ALL of tile 0, THEN all of tile 1 ----
  // wave w stages cb=w: subtiles u = w*6 + j, j=(ks<<1)|h2
  const unsigned char* bsrc =
      B8 + (size_t)(colbase + w * 16 + sub) * D_DIM + grp * 32;
#pragma unroll
  for (int j = 0; j < 6; ++j)
    GLDS(bsrc + (j >> 1) * 128 + (j & 1) * 16, LDS + (w * 6 + j) * 1024);
#pragma unroll
  for (int j = 0; j < 6; ++j)
    GLDS(bsrc + BUFSZ + (j >> 1) * 128 + (j & 1) * 16,
         LDS + BUFSZ + (w * 6 + j) * 1024);
  bsrc += 2 * BUFSZ;

  unsigned t01[4][9];  // packed (rbl0 lo, rbl1 hi) lists, rows grp*4+i / +16
  unsigned t2[2][9];   // packed (rbl2 i=2p lo, i=2p+1 hi) lists, rows 32+...
#pragma unroll
  for (int i = 0; i < 4; ++i)
#pragma unroll
    for (int j = 0; j < 9; ++j) t01[i][j] = 0xFFFFFFFFu;
#pragma unroll
  for (int p = 0; p < 2; ++p)
#pragma unroll
    for (int j = 0; j < 9; ++j) t2[p][j] = 0xFFFFFFFFu;

  for (int t = 0; t < TILES; ++t) {
    const int bufo = (t & 1) * BUFSZ;
    if (t + 1 < TILES) asm volatile("s_waitcnt vmcnt(6)" ::: "memory");
    else               asm volatile("s_waitcnt vmcnt(0)" ::: "memory");
    __builtin_amdgcn_s_barrier();

    const unsigned char* br = LDS + bufo + lane * 16;
#pragma unroll
    for (int cb = 0; cb < 4; ++cb) {
      unsigned yu = *(const unsigned short*)(
          &LDS[YS_OFF + ((t * BN + cb * 16 + sub) << 1)]);
      float ysv = (float)yu * (1.0f / 65535.0f);

      f32x4 c0 = {0.f,0.f,0.f,0.f}, c1 = {0.f,0.f,0.f,0.f}, c2 = {0.f,0.f,0.f,0.f};
      __builtin_amdgcn_s_setprio(1);
#pragma unroll
      for (int ks = 0; ks < KS; ++ks) {
        i32x8 b;
        const unsigned char* p = br + cb * 6144 + ks * 2048;
        *(i32x4*)&b = *(const i32x4*)p;
        *((i32x4*)&b + 1) = *(const i32x4*)(p + 1024);
        c0 = MF(af[0][ks], b, c0);
        c1 = MF(af[1][ks], b, c1);
        c2 = MF(af[2][ks], b, c2);
      }
      __builtin_amdgcn_s_setprio(0);

#pragma unroll
      for (int i = 0; i < 4; ++i) {
        float d2a = fmaf(c0[i], M2S, ysv);
        float d2b = fmaf(c1[i], M2S, ysv);
        unsigned dp;
        asm("v_cvt_pknorm_u16_f32 %0, %1, %2" : "=v"(dp) : "v"(d2a), "v"(d2b));
        ins9(t01[i], dp);
      }
#pragma unroll
      for (int p = 0; p < 2; ++p) {
        float d2a = fmaf(c2[2 * p], M2S, ysv);
        float d2b = fmaf(c2[2 * p + 1], M2S, ysv);
        unsigned dp;
        asm("v_cvt_pknorm_u16_f32 %0, %1, %2" : "=v"(dp) : "v"(d2a), "v"(d2b));
        ins9(t2[p], dp);
      }
    }
    __builtin_amdgcn_s_barrier();  // all waves done reading buf[t&1]

    if (t + 2 < TILES) {
#pragma unroll
      for (int j = 0; j < 6; ++j)
        GLDS(bsrc + (j >> 1) * 128 + (j & 1) * 16,
             LDS + bufo + (w * 6 + j) * 1024);
      bsrc += BUFSZ;
    }
  }

  // ---- unpack + per-row merge across 16 sub-lanes; write f32 key partials ----
  float* pbase = part + (size_t)mq * NPAD * K_NB;
  const int wr0 = row0 + w * RW;
#pragma unroll
  for (int i = 0; i < 4; ++i) {
    unsigned ta[9], tb[9];
#pragma unroll
    for (int j = 0; j < 9; ++j) { ta[j] = t01[i][j] & 0xFFFFu; tb[j] = t01[i][j] >> 16; }
    merge16i(ta, pbase + (size_t)(wr0 + grp * 4 + i) * K_NB, sub);
    merge16i(tb, pbase + (size_t)(wr0 + 16 + grp * 4 + i) * K_NB, sub);
  }
#pragma unroll
  for (int p = 0; p < 2; ++p) {
    unsigned ta[9], tb[9];
#pragma unroll
    for (int j = 0; j < 9; ++j) { ta[j] = t2[p][j] & 0xFFFFu; tb[j] = t2[p][j] >> 16; }
    merge16i(ta, pbase + (size_t)(wr0 + 32 + grp * 4 + 2 * p) * K_NB, sub);
    merge16i(tb, pbase + (size_t)(wr0 + 32 + grp * 4 + 2 * p + 1) * K_NB, sub);
  }
}

// ---- merge 4 sorted-9 lists into one sorted-9 (branchless, static idx) ----
__device__ __forceinline__ void merge4lists(float l[4][9], float o[9]) {
#pragma unroll
  for (int s = 0; s < K_NB; ++s) {
    float m = fminf(fminf(l[0][0], l[1][0]), fminf(l[2][0], l[3][0]));
    o[s] = m;
    bool t0 = (l[0][0] == m);
    bool t1 = (l[1][0] == m) && !t0;
    bool t2 = (l[2][0] == m) && !t0 && !t1;
    bool t3 = !(t0 || t1 || t2);
#pragma unroll
    for (int j = 0; j < 8; ++j) {
      l[0][j] = t0 ? l[0][j + 1] : l[0][j];
      l[1][j] = t1 ? l[1][j + 1] : l[1][j];
      l[2][j] = t2 ? l[2][j + 1] : l[2][j];
      l[3][j] = t3 ? l[3][j + 1] : l[3][j];
    }
    l[0][8] = t0 ? BIGF : l[0][8];
    l[1][8] = t1 ? BIGF : l[1][8];
    l[2][8] = t2 ? BIGF : l[2][8];
    l[3][8] = t3 ? BIGF : l[3][8];
  }
}

// ------- merge the 8 M-slice partials, add x^2, sqrt, final output -------
__global__ __launch_bounds__(256) void FAPM_merge8(
    const float* __restrict__ part, const float* __restrict__ xn,
    float* __restrict__ out) {
  const int r = blockIdx.x * 256 + threadIdx.x;
  const float xr = xn[r];
  float l[4][9], a[9], b[9];
#pragma unroll
  for (int q = 0; q < 4; ++q)
#pragma unroll
    for (int j = 0; j < 9; ++j)
      l[q][j] = part[(size_t)q * NPAD * K_NB + (size_t)r * K_NB + j];
  merge4lists(l, a);
#pragma unroll
  for (int q = 0; q < 4; ++q)
#pragma unroll
    for (int j = 0; j < 9; ++j)
      l[q][j] = part[(size_t)(q + 4) * NPAD * K_NB + (size_t)r * K_NB + j];
  merge4lists(l, b);
#pragma unroll
  for (int s = 0; s < K_NB; ++s) {
    bool ta = a[0] <= b[0];
    float m = ta ? a[0] : b[0];
    out[(size_t)r * K_NB + s] = sqrtf(fmaxf(m + xr, 0.f));
#pragma unroll
    for (int j = 0; j < 8; ++j) {
      float an = a[j + 1], bn = b[j + 1];
      a[j] = ta ? an : a[j];
      b[j] = ta ? b[j] : bn;
    }
    a[8] = ta ? BIGF : a[8];
    b[8] = ta ? b[8] : BIGF;
  }
}

extern "C" void kernel_launch(void* const* d_in, const int* in_sizes, int n_in,
                              void* d_out, int out_size, void* d_ws, size_t ws_size,
                              hipStream_t stream) {
  const float* emb = (const float*)d_in[0];
  const float* mem = (const float*)d_in[1];
  float* out = (float*)d_out;
  char* ws = (char*)d_ws;
  size_t offA = 0;
  size_t offB = offA + (size_t)NPAD * D_DIM;         // A8: 12,607,488
  size_t offX = offB + (size_t)M_ROWS * D_DIM;       // B8: +3,145,728
  size_t offY = offX + (size_t)NPAD * 4;             // +131,328
  size_t offP = offY + (size_t)M_ROWS * 4;           // +32,768
  // partials: 8 slices x NPAD x 9 f32 = 9,455,616  (total ~25.4 MB)
  unsigned char* A8 = (unsigned char*)(ws + offA);
  unsigned char* B8 = (unsigned char*)(ws + offB);
  float* xn = (float*)(ws + offX);
  float* yn = (float*)(ws + offY);
  float* part = (float*)(ws + offP);

  FAPM_prep8<<<(NPAD + M_ROWS) / 4, 256, 0, stream>>>(
      emb, mem, (unsigned*)A8, (unsigned*)B8, xn, yn);
  FAPM_fused<<<(NPAD / RB) * NMQ, 256, 0, stream>>>(A8, B8, yn, part);
  FAPM_merge8<<<N_ROWS / 256, 256, 0, stream>>>(part, xn, out);
}

// Round 14
// 193.290 us; speedup vs baseline: 1.2311x; 1.2311x over previous
//
#include <hip/hip_runtime.h>
#include <hip/hip_bf16.h>

#define N_ROWS 32768
#define M_ROWS 8192
#define D_DIM  384
#define K_NB   9
#define BN     64
#define BM     256
#define MQ     (M_ROWS / 4)      // 2048 cols per block
#define TILES  (MQ / BN)         // 32
#define KS     3                 // K steps of 128

// key = y^2 - 2xy quantized: key' = (key + 256) / 2048 in [0,1]
#define QSCALE (1.0f / 2048.0f)
#define YOFF   0.125f            // 256/2048
#define QSTEPF (2048.0f / 65535.0f)
#define QOFFB  256.0f
#define M2S    (-2.0f / 2048.0f)
#define BIGF   3.0e38f

#define YS_OFF 49152             // LDS byte offset of Ys region

typedef __attribute__((ext_vector_type(4))) int      i32x4;
typedef __attribute__((ext_vector_type(8))) int      i32x8;
typedef __attribute__((ext_vector_type(4))) float    f32x4;
typedef __attribute__((ext_vector_type(4))) unsigned u32x4;

#define GLDS(SRC, DST)                                                       \
  __builtin_amdgcn_global_load_lds(                                          \
      (const __attribute__((address_space(1))) void*)(SRC),                  \
      (__attribute__((address_space(3))) void*)(DST), 16, 0, 0)

// ---- prep: f32 -> fp8(e4m3) rows (k-linear) + exact f32 norms ----
__global__ __launch_bounds__(256) void FAPM_prep8(
    const float* __restrict__ emb, const float* __restrict__ mem,
    unsigned* __restrict__ A8, unsigned* __restrict__ B8,
    float* __restrict__ xn, float* __restrict__ yn) {
  const int lane = threadIdx.x & 63;
  const int row  = blockIdx.x * 4 + (threadIdx.x >> 6);
  const float* src;
  unsigned* dst;
  float* nptr;
  if (row < N_ROWS) {
    src = emb + (size_t)row * D_DIM; dst = A8 + (size_t)row * 96; nptr = xn + row;
  } else {
    int r = row - N_ROWS;
    src = mem + (size_t)r * D_DIM; dst = B8 + (size_t)r * 96; nptr = yn + r;
  }
  float s = 0.f;
  {
    int dw = lane;  // dwords 0..63
    f32x4 v = *(const f32x4*)(src + dw * 4);
    s += v.x * v.x + v.y * v.y + v.z * v.z + v.w * v.w;
    int pk = __builtin_amdgcn_cvt_pk_fp8_f32(v.x, v.y, 0, false);
    pk = __builtin_amdgcn_cvt_pk_fp8_f32(v.z, v.w, pk, true);
    dst[dw] = (unsigned)pk;
  }
  if (lane < 32) {
    int dw = lane + 64;  // dwords 64..95
    f32x4 v = *(const f32x4*)(src + dw * 4);
    s += v.x * v.x + v.y * v.y + v.z * v.z + v.w * v.w;
    int pk = __builtin_amdgcn_cvt_pk_fp8_f32(v.x, v.y, 0, false);
    pk = __builtin_amdgcn_cvt_pk_fp8_f32(v.z, v.w, pk, true);
    dst[dw] = (unsigned)pk;
  }
#pragma unroll
  for (int dd = 1; dd < 64; dd <<= 1) s += __shfl_xor(s, dd);
  if (lane == 0) *nptr = s;
}

// packed u16 min/max
__device__ __forceinline__ unsigned pkmin(unsigned a, unsigned b) {
  unsigned d;
  asm("v_pk_min_u16 %0, %1, %2" : "=v"(d) : "v"(a), "v"(b));
  return d;
}
__device__ __forceinline__ unsigned pkmax(unsigned a, unsigned b) {
  unsigned d;
  asm("v_pk_max_u16 %0, %1, %2" : "=v"(d) : "v"(a), "v"(b));
  return d;
}

// ---- 16-lane merge of per-lane sorted u16 lists; writes f32 key ascending ----
__device__ __forceinline__ void merge16i(unsigned t[9], float* dst, int sub) {
  for (int s = 0; s < K_NB; ++s) {
    unsigned m  = t[0];
    int      ml = sub;
#pragma unroll
    for (int dd = 1; dd < 16; dd <<= 1) {
      unsigned ov = (unsigned)__shfl_xor((int)m, dd);
      int      ol = __shfl_xor(ml, dd);
      bool take = (ov < m) || (ov == m && ol < ml);
      m  = take ? ov : m;
      ml = take ? ol : ml;
    }
    if (sub == ml) {
#pragma unroll
      for (int j = 0; j < 8; ++j) t[j] = t[j + 1];
      t[8] = 0xFFFFu;
    }
    if (sub == 0) dst[s] = (float)m * QSTEPF - QOFFB;  // key = y^2 - 2xy
  }
}

// ------- fused: MX-fp8 K=128 MFMA (scales=1), 64 rows/wave, key top-9 -------
__global__ __launch_bounds__(256, 2) void FAPM_fused(
    const unsigned char* __restrict__ A8, const unsigned char* __restrict__ B8,
    const float* __restrict__ yn, float* __restrict__ part) {
  // [0,48K): A stage (prologue, 128 rows/half), then B buf0/buf1 (24KB each)
  //   per (rb,ks) subtile: [h:2][64 lanes][16B]; lane's 32 k-bytes =
  //   ks*128 + (lane>>4)*32 .. +31 of row (lane&15).
  // [48K,52K): Ys as unorm16 of (y^2/2048 + 0.125)
  __shared__ __attribute__((aligned(128))) unsigned char LDS[53248];
  const int tid  = threadIdx.x;
  const int lane = tid & 63;
  const int w    = tid >> 6;          // wave 0..3
  const int sub  = lane & 15;
  const int grp  = lane >> 4;
  const int bx   = blockIdx.x;
  const int mq   = bx & 3;
  const int row0 = (bx >> 2) * BM;    // block rows; wave owns row0+w*64 .. +63
  const int colbase = mq * MQ;

  // ---- Ys region: 8 y-norms per thread -> unorm16 of key-offset form ----
  {
    const float* yp = yn + colbase + tid * 8;
    f32x4 v0 = *(const f32x4*)yp;
    f32x4 v1 = *(const f32x4*)(yp + 4);
    float a0 = fmaf(v0.x, QSCALE, YOFF), a1 = fmaf(v0.y, QSCALE, YOFF);
    float a2 = fmaf(v0.z, QSCALE, YOFF), a3 = fmaf(v0.w, QSCALE, YOFF);
    float a4 = fmaf(v1.x, QSCALE, YOFF), a5 = fmaf(v1.y, QSCALE, YOFF);
    float a6 = fmaf(v1.z, QSCALE, YOFF), a7 = fmaf(v1.w, QSCALE, YOFF);
    unsigned q0, q1, q2, q3;
    asm("v_cvt_pknorm_u16_f32 %0, %1, %2" : "=v"(q0) : "v"(a0), "v"(a1));
    asm("v_cvt_pknorm_u16_f32 %0, %1, %2" : "=v"(q1) : "v"(a2), "v"(a3));
    asm("v_cvt_pknorm_u16_f32 %0, %1, %2" : "=v"(q2) : "v"(a4), "v"(a5));
    asm("v_cvt_pknorm_u16_f32 %0, %1, %2" : "=v"(q3) : "v"(a6), "v"(a7));
    *(u32x4*)(&LDS[YS_OFF + tid * 16]) = (u32x4){q0, q1, q2, q3};
  }

  i32x8 af[4][KS];  // 96 regs: 4 row-blocks of 16, 3 K-steps of 128

  // ---- stage + read A, two halves of 128 rows through [0,48K) ----
#pragma unroll
  for (int half = 0; half < 2; ++half) {
    const unsigned char* asrc =
        A8 + (size_t)(row0 + half * 128 + (w * 2) * 16 + (lane & 15)) * D_DIM +
        (lane >> 4) * 32;
#pragma unroll
    for (int rb2 = 0; rb2 < 2; ++rb2)
#pragma unroll
      for (int ks = 0; ks < KS; ++ks)
#pragma unroll
        for (int h = 0; h < 2; ++h)
          GLDS(asrc + rb2 * 16 * D_DIM + ks * 128 + h * 16,
               LDS + (((w * 2 + rb2) * KS + ks) * 2 + h) * 1024);
    asm volatile("s_waitcnt vmcnt(0)" ::: "memory");
    __syncthreads();
    if ((w >> 1) == half) {
      const int rbh = (w & 1) * 4;
#pragma unroll
      for (int rbl = 0; rbl < 4; ++rbl)
#pragma unroll
        for (int ks = 0; ks < KS; ++ks) {
          const unsigned char* p =
              LDS + (((rbh + rbl) * KS + ks) * 2) * 1024 + lane * 16;
          *(i32x4*)&af[rbl][ks] = *(const i32x4*)p;
          *((i32x4*)&af[rbl][ks] + 1) = *(const i32x4*)(p + 1024);
        }
    }
    __syncthreads();  // reads drained before overwrite
  }

  // ---- prime 2-deep B pipeline: ALL of tile 0, THEN all of tile 1 ----
  const unsigned char* bsrc =
      B8 + (size_t)(colbase + w * 16 + (lane & 15)) * D_DIM + (lane >> 4) * 32;
#pragma unroll
  for (int ks = 0; ks < KS; ++ks)
#pragma unroll
    for (int h = 0; h < 2; ++h)
      GLDS(bsrc + ks * 128 + h * 16, LDS + w * 6144 + (ks * 2 + h) * 1024);
#pragma unroll
  for (int ks = 0; ks < KS; ++ks)
#pragma unroll
    for (int h = 0; h < 2; ++h)
      GLDS(bsrc + 24576 + ks * 128 + h * 16,
           LDS + 24576 + w * 6144 + (ks * 2 + h) * 1024);
  bsrc += 2 * 24576;

  // ---- phase stagger: break co-resident-block lockstep ----
  // Co-resident blocks launch in phase and have identical deterministic
  // round times; barriers keep them in phase forever -> zero cross-wave
  // MFMA/VALU overlap. Give each block a pseudo-random 0..3 half-phase
  // (~1.5K cyc each) so SIMD-sharing waves land in different phases.
  {
    unsigned ph = ((unsigned)bx * 2654435761u) >> 30;
    for (unsigned z = 0; z < ph * 3u; ++z)
      asm volatile("s_sleep 8" ::: "memory");
  }

  unsigned tkp[2][4][9];  // packed (rbl 2s lo, 2s+1 hi) top-9 keys
#pragma unroll
  for (int s2 = 0; s2 < 2; ++s2)
#pragma unroll
    for (int i = 0; i < 4; ++i)
#pragma unroll
      for (int j = 0; j < 9; ++j) tkp[s2][i][j] = 0xFFFFFFFFu;

  for (int t = 0; t < TILES; ++t) {
    const int bufo = (t & 1) * 24576;
    if (t + 1 < TILES) asm volatile("s_waitcnt vmcnt(6)" ::: "memory");
    else               asm volatile("s_waitcnt vmcnt(0)" ::: "memory");
    __builtin_amdgcn_s_barrier();

    const unsigned char* br = LDS + bufo + lane * 16;
#pragma unroll
    for (int cb = 0; cb < 4; ++cb) {
      unsigned yu = *(const unsigned short*)(
          &LDS[YS_OFF + ((t * 64 + cb * 16 + sub) << 1)]);
      float ysv = (float)yu * (1.0f / 65535.0f);

      i32x8 bf[KS];
#pragma unroll
      for (int ks = 0; ks < KS; ++ks) {
        const unsigned char* p = br + cb * 6144 + ks * 2048;
        *(i32x4*)&bf[ks] = *(const i32x4*)p;
        *((i32x4*)&bf[ks] + 1) = *(const i32x4*)(p + 1024);
      }
      f32x4 acc[4];
#pragma unroll
      for (int rbl = 0; rbl < 4; ++rbl) acc[rbl] = (f32x4){0.f, 0.f, 0.f, 0.f};
      __builtin_amdgcn_s_setprio(1);
#pragma unroll
      for (int ks = 0; ks < KS; ++ks)
#pragma unroll
        for (int rbl = 0; rbl < 4; ++rbl)
          acc[rbl] = __builtin_amdgcn_mfma_scale_f32_16x16x128_f8f6f4(
              af[rbl][ks], bf[ks], acc[rbl], 0, 0,
              0, 0x7F7F7F7F, 0, 0x7F7F7F7F);  // E8M0 scales = 1.0
      __builtin_amdgcn_s_setprio(0);

#pragma unroll
      for (int s2 = 0; s2 < 2; ++s2)
#pragma unroll
        for (int i = 0; i < 4; ++i) {
          float d2a = fmaf(acc[2 * s2][i], M2S, ysv);
          float d2b = fmaf(acc[2 * s2 + 1][i], M2S, ysv);
          unsigned dp;
          asm("v_cvt_pknorm_u16_f32 %0, %1, %2" : "=v"(dp) : "v"(d2a), "v"(d2b));
#pragma unroll
          for (int j = 8; j >= 1; --j)
            tkp[s2][i][j] = pkmin(tkp[s2][i][j], pkmax(dp, tkp[s2][i][j - 1]));
          tkp[s2][i][0] = pkmin(tkp[s2][i][0], dp);
        }
    }
    __builtin_amdgcn_s_barrier();  // all waves done reading buf[t&1]

    if (t + 2 < TILES) {
#pragma unroll
      for (int ks = 0; ks < KS; ++ks)
#pragma unroll
        for (int h = 0; h < 2; ++h)
          GLDS(bsrc + ks * 128 + h * 16,
               LDS + bufo + w * 6144 + (ks * 2 + h) * 1024);
      bsrc += 24576;
    }
  }

  // ---- unpack + per-row merge across 16 sub-lanes; write f32 key partials ----
  float* pbase = part + (size_t)mq * N_ROWS * K_NB;
#pragma unroll
  for (int s2 = 0; s2 < 2; ++s2)
#pragma unroll
    for (int i = 0; i < 4; ++i) {
      unsigned ta[9], tb[9];
#pragma unroll
      for (int j = 0; j < 9; ++j) {
        ta[j] = tkp[s2][i][j] & 0xFFFFu;
        tb[j] = tkp[s2][i][j] >> 16;
      }
      int rowA = row0 + w * 64 + (2 * s2) * 16 + grp * 4 + i;
      merge16i(ta, pbase + (size_t)rowA * K_NB, sub);
      merge16i(tb, pbase + (size_t)(rowA + 16) * K_NB, sub);
    }
}

// ------- merge the four M-quarter partials, add x^2, sqrt, final output -------
__global__ __launch_bounds__(256) void FAPM_merge4(
    const float* __restrict__ part, const float* __restrict__ xn,
    float* __restrict__ out) {
  const int r = blockIdx.x * 256 + threadIdx.x;
  const float xr = xn[r];
  float l[4][9];
#pragma unroll
  for (int q = 0; q < 4; ++q)
#pragma unroll
    for (int j = 0; j < 9; ++j)
      l[q][j] = part[(size_t)q * N_ROWS * K_NB + (size_t)r * K_NB + j];
#pragma unroll
  for (int s = 0; s < K_NB; ++s) {
    float m = fminf(fminf(l[0][0], l[1][0]), fminf(l[2][0], l[3][0]));
    out[(size_t)r * K_NB + s] = sqrtf(fmaxf(m + xr, 0.f));
    bool t0 = (l[0][0] == m);
    bool t1 = (l[1][0] == m) && !t0;
    bool t2 = (l[2][0] == m) && !t0 && !t1;
    bool t3 = !(t0 || t1 || t2);
#pragma unroll
    for (int j = 0; j < 8; ++j) {
      l[0][j] = t0 ? l[0][j + 1] : l[0][j];
      l[1][j] = t1 ? l[1][j + 1] : l[1][j];
      l[2][j] = t2 ? l[2][j + 1] : l[2][j];
      l[3][j] = t3 ? l[3][j + 1] : l[3][j];
    }
    l[0][8] = t0 ? BIGF : l[0][8];
    l[1][8] = t1 ? BIGF : l[1][8];
    l[2][8] = t2 ? BIGF : l[2][8];
    l[3][8] = t3 ? BIGF : l[3][8];
  }
}

extern "C" void kernel_launch(void* const* d_in, const int* in_sizes, int n_in,
                              void* d_out, int out_size, void* d_ws, size_t ws_size,
                              hipStream_t stream) {
  const float* emb = (const float*)d_in[0];
  const float* mem = (const float*)d_in[1];
  float* out = (float*)d_out;
  char* ws = (char*)d_ws;
  size_t offA = 0;
  size_t offB = offA + (size_t)N_ROWS * D_DIM;       // A8: 12,582,912
  size_t offX = offB + (size_t)M_ROWS * D_DIM;       // B8: +3,145,728
  size_t offY = offX + (size_t)N_ROWS * 4;           // +131,072
  size_t offP = offY + (size_t)M_ROWS * 4;           // +32,768
  // partials: 4 quarters x N x 9 f32 = 4,718,592  (total ~20.6 MB)
  unsigned char* A8 = (unsigned char*)(ws + offA);
  unsigned char* B8 = (unsigned char*)(ws + offB);
  float* xn = (float*)(ws + offX);
  float* yn = (float*)(ws + offY);
  float* part = (float*)(ws + offP);

  FAPM_prep8<<<(N_ROWS + M_ROWS) / 4, 256, 0, stream>>>(
      emb, mem, (unsigned*)A8, (unsigned*)B8, xn, yn);
  FAPM_fused<<<(N_ROWS / 128) * 2, 256, 0, stream>>>(A8, B8, yn, part);
  FAPM_merge4<<<N_ROWS / 256, 256, 0, stream>>>(part, xn, out);
}